// Round 3
// baseline (173.575 us; speedup 1.0000x reference)
//
#include <hip/hip_runtime.h>
#include <math.h>

// Voxelized chamfer loss, single-P formulation:
//   P[b,i,j] = ||vox(pred_bi) - vox(gt_bj)||^2  (exact small integers in fp32)
//   loss = mean_i min_j P + mean_j min_i P
// Key: BOTH direction terms come from the SAME P — compute each pairwise
// distance once, reduce along rows (dist1) and columns (dist2) simultaneously.
//
// kernel1: 512 blocks = (batch b, 32-row tile rb). Stages all 4096 voxelized
// gt candidates in LDS. Each wave holds 8 pred queries in registers (packed
// v2f -> v_pk_*_f32); each lane owns 64 candidates and keeps their running
// column-mins in 64 VGPRs. Row-mins reduce cross-lane via shuffles -> exact
// integer sum -> rowPart. Column-mins combine across the block's 4 waves via
// reused LDS -> one colPart row per block.
// kernel2: 64 blocks min-combine colPart across the 128 row-blocks, sum, and
// atomicAdd exact multiples of 2^-14 into d_out (order-independent: every
// value is integer * 2^-14 with all intermediates < 2^24 * 2^-14).

typedef float v2f __attribute__((ext_vector_type(2)));

constexpr int NPTS  = 4096;
constexpr int BLK   = 256;
constexpr int QPB   = 32;             // pred rows per block
constexpr int NRB   = NPTS / QPB;     // 128 row-blocks per batch
constexpr int BATCH = 4;
constexpr float FINF  = 3.402823466e38f;
constexpr float SCALE = 1.0f / 16384.0f;   // 1/(B*N) = 2^-14, exact

__device__ __forceinline__ float vox(float c, float off) {
    return truncf((c + off) / 0.05f);  // keep IEEE divide: matches reference
}

__global__ __launch_bounds__(BLK, 2) void chamfer_tile_kernel(
    const float* __restrict__ preds,
    const float* __restrict__ gts,
    float* __restrict__ colPart,   // [BATCH*NRB][NPTS]
    float* __restrict__ rowPart,   // [BATCH*NRB*4]
    float* __restrict__ out)
{
    __shared__ __align__(16) float smem[3 * NPTS];
    float* sx = smem;
    float* sy = smem + NPTS;
    float* sz = smem + 2 * NPTS;

    const int t   = threadIdx.x;
    const int bid = blockIdx.x;
    const int b   = bid / NRB;
    const int rb  = bid - b * NRB;

    if (bid == 0 && t == 0) out[0] = 0.0f;   // accumulator for kernel 2

    const float* __restrict__ xb = preds + (size_t)b * NPTS * 3;
    const float* __restrict__ yb = gts   + (size_t)b * NPTS * 3;

    // Stage + voxelize all gt candidates (SoA in LDS).
    for (int cand = t; cand < NPTS; cand += BLK) {
        sx[cand] = vox(yb[cand * 3 + 0], 3.0f);
        sy[cand] = vox(yb[cand * 3 + 1], 3.0f);
        sz[cand] = vox(yb[cand * 3 + 2], 1.0f);
    }

    const int w  = t >> 6;   // wave 0..3 -> query group of 8
    const int cg = t & 63;   // lane -> candidate chunk

    v2f qx[4], qy[4], qz[4];
    const int qbase = rb * QPB + w * 8;
    #pragma unroll
    for (int p = 0; p < 4; ++p) {
        const int q0 = qbase + 2 * p, q1 = q0 + 1;
        qx[p] = (v2f){ vox(xb[q0*3+0], 3.0f), vox(xb[q1*3+0], 3.0f) };
        qy[p] = (v2f){ vox(xb[q0*3+1], 3.0f), vox(xb[q1*3+1], 3.0f) };
        qz[p] = (v2f){ vox(xb[q0*3+2], 1.0f), vox(xb[q1*3+2], 1.0f) };
    }

    __syncthreads();

    v2f m[4];
    #pragma unroll
    for (int p = 0; p < 4; ++p) m[p] = (v2f){FINF, FINF};
    float colmin[64];                 // per-lane running col-mins (static idx)
    #pragma unroll
    for (int i = 0; i < 64; ++i) colmin[i] = FINF;

    #pragma unroll
    for (int jj = 0; jj < NPTS / 256; ++jj) {      // fully unrolled: 16 iters
        const int base = jj * 256 + cg * 4;
        const float4 cx4 = *reinterpret_cast<const float4*>(&sx[base]);
        const float4 cy4 = *reinterpret_cast<const float4*>(&sy[base]);
        const float4 cz4 = *reinterpret_cast<const float4*>(&sz[base]);
        const float cxa[4] = {cx4.x, cx4.y, cx4.z, cx4.w};
        const float cya[4] = {cy4.x, cy4.y, cy4.z, cy4.w};
        const float cza[4] = {cz4.x, cz4.y, cz4.z, cz4.w};
        #pragma unroll
        for (int k = 0; k < 4; ++k) {
            v2f d[4];
            #pragma unroll
            for (int p = 0; p < 4; ++p) {
                v2f dx = qx[p] - cxa[k];
                v2f dy = qy[p] - cya[k];
                v2f dz = qz[p] - cza[k];
                d[p] = dx * dx + dy * dy + dz * dz;
                m[p].x = fminf(m[p].x, d[p].x);    // row-min (dist1)
                m[p].y = fminf(m[p].y, d[p].y);
            }
            // col-min over this candidate's 8 query distances (min3 trees)
            float c0 = fminf(fminf(d[0].x, d[0].y), d[1].x);
            float c1 = fminf(fminf(d[1].y, d[2].x), d[2].y);
            float c2 = fminf(fminf(d[3].x, d[3].y), c0);
            colmin[jj*4 + k] = fminf(fminf(c1, c2), colmin[jj*4 + k]);
        }
    }

    // dist1: cross-lane min per query, sum the wave's 8 mins (exact ints).
    float mm[8];
    #pragma unroll
    for (int p = 0; p < 4; ++p) { mm[2*p] = m[p].x; mm[2*p+1] = m[p].y; }
    #pragma unroll
    for (int i = 0; i < 8; ++i) {
        float v = mm[i];
        #pragma unroll
        for (int o = 32; o >= 1; o >>= 1)
            v = fminf(v, __shfl_xor(v, o, 64));
        mm[i] = v;
    }
    if (cg == 0) {
        float s = 0.0f;
        #pragma unroll
        for (int i = 0; i < 8; ++i) s += mm[i];
        rowPart[bid * 4 + w] = s;
    }

    // dist2: combine the 4 waves' column mins via reused LDS, store one row.
    __syncthreads();                                // all done reading smem
    if (w > 0) {
        #pragma unroll
        for (int jj = 0; jj < 16; ++jj) {
            float4 v = { colmin[jj*4+0], colmin[jj*4+1],
                         colmin[jj*4+2], colmin[jj*4+3] };
            *reinterpret_cast<float4*>(&smem[(w-1)*NPTS + jj*256 + cg*4]) = v;
        }
    }
    __syncthreads();
    if (w == 0) {
        float* dst = colPart + (size_t)bid * NPTS;
        #pragma unroll
        for (int jj = 0; jj < 16; ++jj) {
            const int base = jj * 256 + cg * 4;
            const float4 a  = *reinterpret_cast<const float4*>(&smem[base]);
            const float4 bb = *reinterpret_cast<const float4*>(&smem[NPTS + base]);
            const float4 c  = *reinterpret_cast<const float4*>(&smem[2*NPTS + base]);
            float4 r;
            r.x = fminf(fminf(colmin[jj*4+0], a.x), fminf(bb.x, c.x));
            r.y = fminf(fminf(colmin[jj*4+1], a.y), fminf(bb.y, c.y));
            r.z = fminf(fminf(colmin[jj*4+2], a.z), fminf(bb.z, c.z));
            r.w = fminf(fminf(colmin[jj*4+3], a.w), fminf(bb.w, c.w));
            *reinterpret_cast<float4*>(&dst[base]) = r;
        }
    }
}

__global__ __launch_bounds__(BLK) void chamfer_finish_kernel(
    const float* __restrict__ colPart,
    const float* __restrict__ rowPart,
    float* __restrict__ out)
{
    __shared__ float red[BLK];
    const int t = threadIdx.x;
    const int g = blockIdx.x;              // 64 blocks: b = g>>4
    const int b = g >> 4;
    const int j = ((g & 15) << 8) + t;

    const float* col = colPart + (size_t)b * NRB * NPTS + j;
    float cm = FINF;
    #pragma unroll 8
    for (int rb = 0; rb < NRB; ++rb)
        cm = fminf(cm, col[(size_t)rb * NPTS]);   // coalesced across threads

    float tot = cm;
    if (g == 0) {                          // fold in the dist1 partials once
        float s = 0.0f;
        for (int i = t; i < BATCH * NRB * 4; i += BLK) s += rowPart[i];
        tot += s;
    }
    red[t] = tot;
    __syncthreads();
    for (int k = 128; k > 0; k >>= 1) {
        if (t < k) red[t] += red[t + k];
        __syncthreads();
    }
    // Each block adds an exact multiple of 2^-14 -> order-independent.
    if (t == 0) atomicAdd(out, red[0] * SCALE);
}

extern "C" void kernel_launch(void* const* d_in, const int* in_sizes, int n_in,
                              void* d_out, int out_size, void* d_ws, size_t ws_size,
                              hipStream_t stream)
{
    const float* preds = (const float*)d_in[0];
    const float* gts   = (const float*)d_in[1];
    float* out = (float*)d_out;
    float* colPart = (float*)d_ws;                              // 8 MB
    float* rowPart = colPart + (size_t)BATCH * NRB * NPTS;      // 2048 floats

    chamfer_tile_kernel<<<BATCH * NRB, BLK, 0, stream>>>(
        preds, gts, colPart, rowPart, out);
    chamfer_finish_kernel<<<BATCH * NPTS / BLK, BLK, 0, stream>>>(
        colPart, rowPart, out);
}

// Round 4
// 49.975 us; speedup vs baseline: 3.4732x; 3.4732x over previous
//
#include <hip/hip_runtime.h>
#include <math.h>

// Voxelized chamfer, single-P formulation, spill-free:
//   P[b,i,j] = ||vox(pred_bi) - vox(gt_bj)||^2  (exact small ints in fp32)
//   loss = mean_i min_j P + mean_j min_i P   — both terms from ONE P pass.
//
// kernel1: 512 blocks = (batch, 32-query row tile). Each of 4 waves holds the
// block's 32 voxelized queries in registers (16 v2f per coord) and owns a
// private 1024-candidate slice, 16 candidates per lane, loaded directly from
// global (48 B contiguous per lane — no candidate LDS). Per candidate:
//   - 32 distances via packed v2f math (v_pk_sub/fma)
//   - col-min over the 32 queries (min3 chains) -> IMMEDIATE float4 store to
//     colPart (write-once: no persistent col-min registers -> no spill)
//   - row-min accumulated in 16 v2f regs
// Row-mins reduce via padded LDS transpose (conflict-free) + cross-wave min,
// then an exact integer sum -> rowPart[block].
// kernel2: min-combine colPart across the 128 row-tiles, fold rowPart, and
// atomicAdd exact multiples of 2^-14 into d_out (order-independent).

typedef float v2f __attribute__((ext_vector_type(2)));

constexpr int NPTS  = 4096;
constexpr int BLK   = 256;
constexpr int QPB   = 32;             // queries (pred rows) per block
constexpr int NRB   = NPTS / QPB;     // 128 row tiles per batch
constexpr int BATCH = 4;
constexpr float FINF  = 3.402823466e38f;
constexpr float SCALE = 1.0f / 16384.0f;   // 1/(B*N) = 2^-14, exact

__device__ __forceinline__ float vox(float c, float off) {
    return truncf((c + off) / 0.05f);  // IEEE divide: bit-matches reference
}

__global__ __launch_bounds__(BLK) void chamfer_tile_kernel(
    const float* __restrict__ preds,
    const float* __restrict__ gts,
    float* __restrict__ colPart,   // [BATCH*NRB][NPTS]
    float* __restrict__ rowPart,   // [BATCH*NRB]
    float* __restrict__ out)
{
    __shared__ float redT[4][64][QPB + 1];   // +1 pad: conflict-free transpose
    __shared__ float waveRed[4][QPB];

    const int t    = threadIdx.x;
    const int bid  = blockIdx.x;
    const int b    = bid / NRB;
    const int rb   = bid - b * NRB;
    const int w    = t >> 6;
    const int lane = t & 63;

    if (bid == 0 && t == 0) out[0] = 0.0f;   // accumulator for kernel 2

    const float* __restrict__ xb = preds + (size_t)b * NPTS * 3;
    const float* __restrict__ yb = gts   + (size_t)b * NPTS * 3;

    // The block's 32 queries, voxelized, packed (uniform across waves/lanes).
    v2f qx[16], qy[16], qz[16];
    const int qbase = rb * QPB;
    #pragma unroll
    for (int p = 0; p < 16; ++p) {
        const int q0 = qbase + 2 * p, q1 = q0 + 1;
        qx[p] = (v2f){ vox(xb[q0*3+0], 3.0f), vox(xb[q1*3+0], 3.0f) };
        qy[p] = (v2f){ vox(xb[q0*3+1], 3.0f), vox(xb[q1*3+1], 3.0f) };
        qz[p] = (v2f){ vox(xb[q0*3+2], 1.0f), vox(xb[q1*3+2], 1.0f) };
    }

    v2f m[16];
    #pragma unroll
    for (int p = 0; p < 16; ++p) m[p] = (v2f){FINF, FINF};

    const int slice = w * 1024;
    float* __restrict__ colDst = colPart + (size_t)bid * NPTS;

    #pragma unroll
    for (int g = 0; g < 4; ++g) {
        const int cb = slice + g * 256 + lane * 4;   // 4 candidates, 48 B
        const float4 r0 = *reinterpret_cast<const float4*>(&yb[cb * 3 + 0]);
        const float4 r1 = *reinterpret_cast<const float4*>(&yb[cb * 3 + 4]);
        const float4 r2 = *reinterpret_cast<const float4*>(&yb[cb * 3 + 8]);
        const float cxr[4] = {r0.x, r0.w, r1.z, r2.y};
        const float cyr[4] = {r0.y, r1.x, r1.w, r2.z};
        const float czr[4] = {r0.z, r1.y, r2.x, r2.w};
        float colarr[4];
        #pragma unroll
        for (int k = 0; k < 4; ++k) {
            const float vx = vox(cxr[k], 3.0f);
            const float vy = vox(cyr[k], 3.0f);
            const float vz = vox(czr[k], 1.0f);
            float cm = FINF;
            #pragma unroll
            for (int p = 0; p < 16; ++p) {
                v2f dx = qx[p] - vx, dy = qy[p] - vy, dz = qz[p] - vz;
                v2f d  = dx * dx + dy * dy + dz * dz;
                m[p].x = fminf(m[p].x, d.x);          // row-min (dist1)
                m[p].y = fminf(m[p].y, d.y);
                cm = fminf(fminf(cm, d.x), d.y);      // col-min -> v_min3
            }
            colarr[k] = cm;
        }
        const float4 colv = {colarr[0], colarr[1], colarr[2], colarr[3]};
        *reinterpret_cast<float4*>(&colDst[cb]) = colv;  // write-once, coalesced
    }

    // --- dist1 row-min reduction: padded-LDS transpose within each wave ---
    #pragma unroll
    for (int p = 0; p < 16; ++p) {
        redT[w][lane][2*p]     = m[p].x;
        redT[w][lane][2*p + 1] = m[p].y;
    }
    // (same-wave RAW on LDS: compiler inserts lgkmcnt; no barrier needed yet)
    const int h = lane >> 5, q = lane & 31;
    float v = FINF;
    #pragma unroll
    for (int i = 0; i < 32; ++i)
        v = fminf(v, redT[w][h * 32 + i][q]);
    v = fminf(v, __shfl_xor(v, 32, 64));      // combine the two lane halves
    if (lane < 32) waveRed[w][q] = v;

    __syncthreads();
    if (w == 0) {
        float r = 0.0f;
        if (lane < 32) {
            r = fminf(fminf(waveRed[0][q], waveRed[1][q]),
                      fminf(waveRed[2][q], waveRed[3][q]));
        }
        #pragma unroll
        for (int o = 32; o >= 1; o >>= 1) r += __shfl_xor(r, o, 64);
        if (lane == 0) rowPart[bid] = r;      // exact int sum of 32 row-mins
    }
}

__global__ __launch_bounds__(BLK) void chamfer_finish_kernel(
    const float* __restrict__ colPart,
    const float* __restrict__ rowPart,
    float* __restrict__ out)
{
    __shared__ float red[BLK];
    const int t = threadIdx.x;
    const int g = blockIdx.x;              // 64 blocks: b = g>>4
    const int b = g >> 4;
    const int j = ((g & 15) << 8) + t;

    const float* col = colPart + (size_t)b * NRB * NPTS + j;
    float cm = FINF;
    #pragma unroll 8
    for (int rb = 0; rb < NRB; ++rb)
        cm = fminf(cm, col[(size_t)rb * NPTS]);   // coalesced across threads

    float tot = cm;
    if (g == 0) {                          // fold dist1 partials once
        float s = 0.0f;
        for (int i = t; i < BATCH * NRB; i += BLK) s += rowPart[i];
        tot += s;
    }
    red[t] = tot;
    __syncthreads();
    for (int k = 128; k > 0; k >>= 1) {
        if (t < k) red[t] += red[t + k];
        __syncthreads();
    }
    // Each block adds an exact multiple of 2^-14 -> order-independent.
    if (t == 0) atomicAdd(out, red[0] * SCALE);
}

extern "C" void kernel_launch(void* const* d_in, const int* in_sizes, int n_in,
                              void* d_out, int out_size, void* d_ws, size_t ws_size,
                              hipStream_t stream)
{
    const float* preds = (const float*)d_in[0];
    const float* gts   = (const float*)d_in[1];
    float* out = (float*)d_out;
    float* colPart = (float*)d_ws;                              // 8 MB
    float* rowPart = colPart + (size_t)BATCH * NRB * NPTS;      // 512 floats

    chamfer_tile_kernel<<<BATCH * NRB, BLK, 0, stream>>>(
        preds, gts, colPart, rowPart, out);
    chamfer_finish_kernel<<<BATCH * NPTS / BLK, BLK, 0, stream>>>(
        colPart, rowPart, out);
}

// Round 5
// 39.214 us; speedup vs baseline: 4.4264x; 1.2744x over previous
//
#include <hip/hip_runtime.h>
#include <math.h>

// Voxelized chamfer, single-P formulation:
//   P[b,i,j] = ||vox(pred_bi) - vox(gt_bj)||^2  (exact small ints in fp32)
//   loss = mean_i min_j P + mean_j min_i P   — both terms from ONE P pass.
//
// k0: voxelize both clouds once into SoA [b][coord][idx] (ALL fp32 divides
//     happen here, bit-identical to the reference), zero the output accum.
// k1: 512 blocks = (batch, 32-query tile). The block's 32 voxelized queries
//     are uniform scalar loads (broadcast); each of 4 waves owns a private
//     1024-candidate slice read as perfectly-coalesced SoA float4. Scalar
//     fmaf/fminf math: 3 sub + mul + 2 fma + 2 min per eval. Col-min per
//     candidate is write-once -> float4 store to colPart (no persistent
//     col regs, no spill). Row-mins reduce via padded-LDS transpose.
// k2: 512 blocks min-combine colPart columns across the 128 row-tiles,
//     fold rowPart, atomicAdd exact multiples of 2^-14 (order-independent:
//     every partial is integer * 2^-14, all intermediates exact).

constexpr int NPTS  = 4096;
constexpr int BLK   = 256;
constexpr int QPB   = 32;             // queries per block
constexpr int NRB   = NPTS / QPB;     // 128 row tiles per batch
constexpr int BATCH = 4;
constexpr float FINF  = 3.402823466e38f;
constexpr float SCALE = 1.0f / 16384.0f;   // 1/(B*N) = 2^-14, exact

// ---------------- k0: voxelize to SoA + zero accumulator ----------------
__global__ __launch_bounds__(BLK) void vox_kernel(
    const float* __restrict__ preds, const float* __restrict__ gts,
    float* __restrict__ qvox, float* __restrict__ cvox,
    float* __restrict__ out)
{
    const int gid = blockIdx.x * BLK + threadIdx.x;   // 0..32767
    if (gid == 0) out[0] = 0.0f;
    const int cloud = gid >> 14;                      // 0: preds, 1: gts
    const int idx   = gid & 16383;
    const int b = idx >> 12, i = idx & 4095;
    const float* src = (cloud ? gts : preds) + (size_t)idx * 3;
    float* dst = (cloud ? cvox : qvox) + (size_t)b * 3 * NPTS + i;
    dst[0]        = truncf((src[0] + 3.0f) / 0.05f);  // IEEE div: bit-exact
    dst[NPTS]     = truncf((src[1] + 3.0f) / 0.05f);
    dst[2 * NPTS] = truncf((src[2] + 1.0f) / 0.05f);
}

// ---------------- k1: main chamfer tile pass ----------------
__global__ __launch_bounds__(BLK) void chamfer_tile_kernel(
    const float* __restrict__ qvox, const float* __restrict__ cvox,
    float* __restrict__ colPart,   // [BATCH*NRB][NPTS]
    float* __restrict__ rowPart)   // [BATCH*NRB]
{
    __shared__ float redT[4][64][QPB + 1];   // +1 pad: conflict-free transpose
    __shared__ float waveRed[4][QPB];

    const int t    = threadIdx.x;
    const int bid  = blockIdx.x;
    const int b    = bid / NRB;
    const int rb   = bid - b * NRB;
    const int w    = t >> 6;
    const int lane = t & 63;

    const float* __restrict__ qb = qvox + (size_t)b * 3 * NPTS;
    const float* __restrict__ cb = cvox + (size_t)b * 3 * NPTS;

    // 32 queries, uniform across the block (broadcast loads).
    float qx[QPB], qy[QPB], qz[QPB];
    #pragma unroll
    for (int q = 0; q < QPB; ++q) {
        const int qi = rb * QPB + q;
        qx[q] = qb[qi];
        qy[q] = qb[NPTS + qi];
        qz[q] = qb[2 * NPTS + qi];
    }
    float rm[QPB];
    #pragma unroll
    for (int q = 0; q < QPB; ++q) rm[q] = FINF;

    float* __restrict__ colDst = colPart + (size_t)bid * NPTS;
    const int slice = w * 1024;

    #pragma unroll 1                      // keep code small; body is big
    for (int g = 0; g < 4; ++g) {
        const int cj = slice + g * 256 + lane * 4;   // 4 candidates, coalesced
        const float4 cx = *reinterpret_cast<const float4*>(&cb[cj]);
        const float4 cy = *reinterpret_cast<const float4*>(&cb[NPTS + cj]);
        const float4 cz = *reinterpret_cast<const float4*>(&cb[2 * NPTS + cj]);
        const float vxs[4] = {cx.x, cx.y, cx.z, cx.w};
        const float vys[4] = {cy.x, cy.y, cy.z, cy.w};
        const float vzs[4] = {cz.x, cz.y, cz.z, cz.w};
        float colv[4];
        #pragma unroll
        for (int k = 0; k < 4; ++k) {
            const float vx = vxs[k], vy = vys[k], vz = vzs[k];
            float cm = FINF;
            #pragma unroll
            for (int q = 0; q < QPB; ++q) {
                const float dx = qx[q] - vx;
                const float dy = qy[q] - vy;
                const float dz = qz[q] - vz;
                const float d  = fmaf(dz, dz, fmaf(dy, dy, dx * dx));
                rm[q] = fminf(rm[q], d);      // row-min (dist1)
                cm    = fminf(cm, d);         // col-min (dist2)
            }
            colv[k] = cm;
        }
        const float4 cv = {colv[0], colv[1], colv[2], colv[3]};
        *reinterpret_cast<float4*>(&colDst[cj]) = cv;   // write-once
    }

    // Row-min reduction: padded-LDS transpose, then cross-wave combine.
    #pragma unroll
    for (int q = 0; q < QPB; ++q) redT[w][lane][q] = rm[q];
    __syncthreads();

    if (t < 128) {                        // (w', q') pairs: min over 64 lanes
        const int wp = t >> 5, qp = t & 31;
        float v = redT[wp][0][qp];
        #pragma unroll
        for (int l = 1; l < 64; ++l) v = fminf(v, redT[wp][l][qp]);
        waveRed[wp][qp] = v;
    }
    __syncthreads();

    if (w == 0) {                         // wave 0: combine + exact int sum
        float v = 0.0f;
        if (lane < 32) {
            v = fminf(fminf(waveRed[0][lane], waveRed[1][lane]),
                      fminf(waveRed[2][lane], waveRed[3][lane]));
        }
        #pragma unroll
        for (int o = 32; o >= 1; o >>= 1) v += __shfl_xor(v, o, 64);
        if (lane == 0) rowPart[bid] = v;
    }
}

// ---------------- k2: column-min combine + final sum ----------------
__global__ __launch_bounds__(BLK) void chamfer_finish_kernel(
    const float* __restrict__ colPart,
    const float* __restrict__ rowPart,
    float* __restrict__ out)
{
    __shared__ float red[8][QPB];
    __shared__ float s1[BLK];

    const int t  = threadIdx.x;
    const int g  = blockIdx.x;            // 512 blocks: (b, 32-j tile)
    const int b  = g >> 7;
    const int jt = g & 127;
    const int rbg = t >> 5, jo = t & 31;
    const int j = jt * QPB + jo;

    const float* __restrict__ col = colPart + (size_t)(b * NRB) * NPTS + j;
    float cm = FINF;
    #pragma unroll
    for (int r = 0; r < 16; ++r)
        cm = fminf(cm, col[(size_t)(rbg * 16 + r) * NPTS]);
    red[rbg][jo] = cm;
    __syncthreads();

    float v = 0.0f;
    if (t < 32) {
        float m = red[0][t];
        #pragma unroll
        for (int r2 = 1; r2 < 8; ++r2) m = fminf(m, red[r2][t]);
        v = m;                            // final col-min for query-col j
    }
    if (g == 0) v += rowPart[t] + rowPart[t + 256];   // fold dist1 once
    s1[t] = v;
    __syncthreads();
    for (int k = 128; k > 0; k >>= 1) {
        if (t < k) s1[t] += s1[t + k];
        __syncthreads();
    }
    // Each block adds an exact multiple of 2^-14 -> order-independent.
    if (t == 0) atomicAdd(out, s1[0] * SCALE);
}

extern "C" void kernel_launch(void* const* d_in, const int* in_sizes, int n_in,
                              void* d_out, int out_size, void* d_ws, size_t ws_size,
                              hipStream_t stream)
{
    const float* preds = (const float*)d_in[0];
    const float* gts   = (const float*)d_in[1];
    float* out = (float*)d_out;

    float* qvox    = (float*)d_ws;                               // 196 KB
    float* cvox    = qvox + (size_t)BATCH * 3 * NPTS;            // 196 KB
    float* colPart = cvox + (size_t)BATCH * 3 * NPTS;            // 8 MB
    float* rowPart = colPart + (size_t)BATCH * NRB * NPTS;       // 2 KB

    vox_kernel<<<(2 * BATCH * NPTS) / BLK, BLK, 0, stream>>>(
        preds, gts, qvox, cvox, out);
    chamfer_tile_kernel<<<BATCH * NRB, BLK, 0, stream>>>(
        qvox, cvox, colPart, rowPart);
    chamfer_finish_kernel<<<4 * NPTS / QPB, BLK, 0, stream>>>(
        colPart, rowPart, out);
}